// Round 13
// baseline (1019.735 us; speedup 1.0000x reference)
//
#include <hip/hip_runtime.h>
#include <cstdio>

// ============================================================================
// ROUND 27: attention 4x4-tile (R15 geometry) minus its conflicts.
// Cycle model (validated on R15/R20/R25/R26): per 64 queries/tile, 4x4/64q
// issues 12.9K LDS cycles vs 2x4/32q's 19.6K - R15 only tied R20 because of
// V-transpose write conflicts (~4K cy). Fix: V is channel-major (R26) ->
// stage V EXACTLY like K (straight row copies, zero transpose writes); PV
// reads V[c][m] rows with XOR swizzle (granule ^= (row>>3)&7) -> 2-way, free.
// FMA values/order bit-identical to R15 -> absmax unchanged. Prefetch after
// tiles-ready barrier (R18-verified). convqkv/conv_r: R26 verbatim.
// ============================================================================

// Keeps the harness-stub identifier name (unused utility).
__global__ __launch_bounds__(256) void CrossModalityPositionAttention_56556129354448_kernel(
    float* dst, float val, int n)
{
  const int i = blockIdx.x * 256 + threadIdx.x;
  if (i < n) dst[i] = val;
}

// ---------------------------------------------------------------------------
// DPP lane-shift helpers (conv halo).
__device__ __forceinline__ float dpp_left(float x) {
  return __int_as_float(__builtin_amdgcn_update_dpp(
      0, __float_as_int(x), 0x111, 0xF, 0xF, true));   // row_shr:1
}
__device__ __forceinline__ float dpp_right(float x) {
  return __int_as_float(__builtin_amdgcn_update_dpp(
      0, __float_as_int(x), 0x101, 0xF, 0xF, true));   // row_shl:1
}

#define CTROWS 18
#define CTSTR  64
#define CTSZ   (CTROWS * CTSTR)   // 1152 floats

// ---------------------------------------------------------------------------
// Fused q/k/v conv3x3 + BN + ReLU (R26 verbatim). Outputs channel-major.
__global__ __launch_bounds__(256, 2) void convqkv_f32(
    const float* __restrict__ f1, const float* __restrict__ f2,
    const float* __restrict__ q_w, const float* __restrict__ q_b,
    const float* __restrict__ q_g, const float* __restrict__ q_be,
    const float* __restrict__ q_m, const float* __restrict__ q_va,
    const float* __restrict__ k_w, const float* __restrict__ k_b,
    const float* __restrict__ k_g, const float* __restrict__ k_be,
    const float* __restrict__ k_m, const float* __restrict__ k_va,
    const float* __restrict__ v_w, const float* __restrict__ v_b,
    const float* __restrict__ v_g, const float* __restrict__ v_be,
    const float* __restrict__ v_m, const float* __restrict__ v_va,
    float* __restrict__ qo, float* __restrict__ ko, float* __restrict__ vo)
{
  __shared__ float tA[2][CTSZ];
  __shared__ float tB[2][CTSZ];

  const int b   = blockIdx.z;
  const int co0 = blockIdx.y * 2;
  const int y0  = blockIdx.x * 16;
  const int t   = threadIdx.x;
  const int ry  = t >> 4;
  const int xg  = t & 15;
  const int x0  = xg * 4;

  float qs[2], qsh[2], ks[2], ksh[2], vs[2], vsh[2];
  #pragma unroll
  for (int cc = 0; cc < 2; ++cc) {
    const int c = co0 + cc;
    float iv;
    iv = q_g[c] * rsqrtf(q_va[c] + 1e-5f);
    qs[cc] = iv; qsh[cc] = q_b[c] * iv + q_be[c] - q_m[c] * iv;
    iv = k_g[c] * rsqrtf(k_va[c] + 1e-5f);
    ks[cc] = iv; ksh[cc] = k_b[c] * iv + k_be[c] - k_m[c] * iv;
    iv = v_g[c] * rsqrtf(v_va[c] + 1e-5f);
    vs[cc] = iv; vsh[cc] = v_b[c] * iv + v_be[c] - v_m[c] * iv;
  }

  const float* srcA = f1 + (size_t)b * 256 * 4096;
  const float* srcB = f2 + (size_t)b * 256 * 4096;

  float4 rA[2][2], rB[2][2];
  const int row0 = t >> 4;
  const int row1 = 16 + (t >> 4);
  const int grp  = t & 15;

  #define LOADREGS(R)                                                         \
    {                                                                         \
      _Pragma("unroll")                                                       \
      for (int s = 0; s < 2; ++s) {                                           \
        const size_t cb = (size_t)((R) * 2 + s) * 4096;                       \
        {                                                                     \
          const int gy = y0 - 1 + row0;                                       \
          float4 a = make_float4(0.f, 0.f, 0.f, 0.f);                         \
          float4 bb = make_float4(0.f, 0.f, 0.f, 0.f);                        \
          if (gy >= 0 && gy <= 63) {                                          \
            a  = *(const float4*)(srcA + cb + gy * 64 + grp * 4);             \
            bb = *(const float4*)(srcB + cb + gy * 64 + grp * 4);             \
          }                                                                   \
          rA[s][0] = a; rB[s][0] = bb;                                        \
        }                                                                     \
        if (t < 32) {                                                         \
          const int gy = y0 - 1 + row1;                                       \
          float4 a = make_float4(0.f, 0.f, 0.f, 0.f);                         \
          float4 bb = make_float4(0.f, 0.f, 0.f, 0.f);                        \
          if (gy >= 0 && gy <= 63) {                                          \
            a  = *(const float4*)(srcA + cb + gy * 64 + grp * 4);             \
            bb = *(const float4*)(srcB + cb + gy * 64 + grp * 4);             \
          }                                                                   \
          rA[s][1] = a; rB[s][1] = bb;                                        \
        }                                                                     \
      }                                                                       \
    }

  float accQ[2][4] = {{0.f}}, accK[2][4] = {{0.f}}, accV[2][4] = {{0.f}};

  LOADREGS(0);

  for (int r = 0; r < 128; ++r) {
    __syncthreads();
    #pragma unroll
    for (int s = 0; s < 2; ++s) {
      *(float4*)(&tA[s][row0 * CTSTR + grp * 4]) = rA[s][0];
      *(float4*)(&tB[s][row0 * CTSTR + grp * 4]) = rB[s][0];
      if (t < 32) {
        *(float4*)(&tA[s][row1 * CTSTR + grp * 4]) = rA[s][1];
        *(float4*)(&tB[s][row1 * CTSTR + grp * 4]) = rB[s][1];
      }
    }
    __syncthreads();
    if (r < 127) LOADREGS(r + 1);

    #pragma unroll
    for (int s = 0; s < 2; ++s) {
      const size_t wb = (size_t)co0 * 2304 + (size_t)(r * 2 + s) * 9;
      float wq0[9], wq1[9], wk0[9], wk1[9], wv0[9], wv1[9];
      #pragma unroll
      for (int j = 0; j < 9; ++j) {
        wq0[j] = q_w[wb + j];        wq1[j] = q_w[wb + 2304 + j];
        wk0[j] = k_w[wb + j];        wk1[j] = k_w[wb + 2304 + j];
        wv0[j] = v_w[wb + j];        wv1[j] = v_w[wb + 2304 + j];
      }

      #pragma unroll
      for (int ky = 0; ky < 3; ++ky) {
        const float4 a4 = *(const float4*)(&tA[s][(ry + ky) * CTSTR + x0]);
        const float4 b4 = *(const float4*)(&tB[s][(ry + ky) * CTSTR + x0]);
        const float ca[6] = {dpp_left(a4.w), a4.x, a4.y, a4.z, a4.w, dpp_right(a4.x)};
        const float cb[6] = {dpp_left(b4.w), b4.x, b4.y, b4.z, b4.w, dpp_right(b4.x)};
        const int kb3 = ky * 3;
        #pragma unroll
        for (int px = 0; px < 4; ++px) {
          accQ[0][px] += cb[px] * wq0[kb3] + cb[px + 1] * wq0[kb3 + 1] + cb[px + 2] * wq0[kb3 + 2];
          accK[0][px] += ca[px] * wk0[kb3] + ca[px + 1] * wk0[kb3 + 1] + ca[px + 2] * wk0[kb3 + 2];
          accV[0][px] += ca[px] * wv0[kb3] + ca[px + 1] * wv0[kb3 + 1] + ca[px + 2] * wv0[kb3 + 2];
          accQ[1][px] += cb[px] * wq1[kb3] + cb[px + 1] * wq1[kb3 + 1] + cb[px + 2] * wq1[kb3 + 2];
          accK[1][px] += ca[px] * wk1[kb3] + ca[px + 1] * wk1[kb3 + 1] + ca[px + 2] * wk1[kb3 + 2];
          accV[1][px] += ca[px] * wv1[kb3] + ca[px + 1] * wv1[kb3 + 1] + ca[px + 2] * wv1[kb3 + 2];
        }
      }
    }
  }

  const size_t ob = ((size_t)b * 64 + co0) * 4096 + (size_t)(y0 + ry) * 64 + x0;
  #pragma unroll
  for (int cc = 0; cc < 2; ++cc) {
    float4 o;
    o.x = fmaxf(accQ[cc][0] * qs[cc] + qsh[cc], 0.f);
    o.y = fmaxf(accQ[cc][1] * qs[cc] + qsh[cc], 0.f);
    o.z = fmaxf(accQ[cc][2] * qs[cc] + qsh[cc], 0.f);
    o.w = fmaxf(accQ[cc][3] * qs[cc] + qsh[cc], 0.f);
    *(float4*)(qo + ob + (size_t)cc * 4096) = o;
    o.x = fmaxf(accK[cc][0] * ks[cc] + ksh[cc], 0.f);
    o.y = fmaxf(accK[cc][1] * ks[cc] + ksh[cc], 0.f);
    o.z = fmaxf(accK[cc][2] * ks[cc] + ksh[cc], 0.f);
    o.w = fmaxf(accK[cc][3] * ks[cc] + ksh[cc], 0.f);
    *(float4*)(ko + ob + (size_t)cc * 4096) = o;
    o.x = fmaxf(accV[cc][0] * vs[cc] + vsh[cc], 0.f);
    o.y = fmaxf(accV[cc][1] * vs[cc] + vsh[cc], 0.f);
    o.z = fmaxf(accV[cc][2] * vs[cc] + vsh[cc], 0.f);
    o.w = fmaxf(accV[cc][3] * vs[cc] + vsh[cc], 0.f);
    *(float4*)(vo + ob + (size_t)cc * 4096) = o;
  }
}

// ---------------------------------------------------------------------------
// Flash attention, fp32.  64 queries/block, grid 256, 4n x 4m thread tile
// (R15 geometry).  K and V both channel-major, both staged as straight row
// copies into [c][m] / [row][m] tiles.  V tile uses XOR granule swizzle
// (granule ^= (row>>3)&7) so PV's 16 mg-lane row reads spread 8 bank-quads.
// P exchanged via kp_lds reuse (R15).  Prefetch after tiles-ready barrier.
__global__ __launch_bounds__(256) void attention_flash_f32(
    const float* __restrict__ q, const float* __restrict__ k,
    const float* __restrict__ v, float* __restrict__ f)
{
  __shared__ float kp_lds[64 * 68];  // K tile [c][m] -> reused as P [n][m]
  __shared__ float vt_lds[64 * 68];  // V tile [c][m], XOR-swizzled granules
  __shared__ float qt_lds[64 * 68];  // Q tile [c][n] -> reused for epilogue

  const int lin = blockIdx.x;
  const int b = (lin & 7) >> 1;
  const int nb = ((lin >> 3) << 1) | (lin & 1);
  const int n0 = nb * 64;

  const int t = threadIdx.x;
  const int mg = t & 15;
  const int ng = t >> 4;

  const float* qb = q + (size_t)b * 64 * 4096;
  const float* kb = k + (size_t)b * 64 * 4096;
  const float* vb = v + (size_t)b * 64 * 4096;

  // ---- stage Q tile [c][n0..n0+63] into qt_lds[c][n] (R15 verbatim)
  {
    const int nn = t & 15;
    const int c0 = t >> 4;
    #pragma unroll
    for (int p = 0; p < 4; ++p) {
      const int c = c0 + p * 16;
      const float4 val = *(const float4*)(qb + (size_t)c * 4096 + n0 + nn * 4);
      *(float4*)(qt_lds + c * 68 + nn * 4) = val;
    }
  }

  float acc[4][4] = {{0.f}};   // O[n_i][c_j]
  float m_run[4], l_run[4];
  #pragma unroll
  for (int i = 0; i < 4; ++i) { m_run[i] = -1e30f; l_run[i] = 0.f; }

  // staging map (K and V identical): row = t>>2 (c), granule base = t&3
  const int kc = t >> 2;
  const int kf = t & 3;
  const int vswz = (kc >> 3) & 7;   // granule XOR for V tile rows

  float4 kreg[4], vreg[4];
  #pragma unroll
  for (int r = 0; r < 4; ++r) {
    kreg[r] = *(const float4*)(kb + (size_t)kc * 4096 + (kf + 4 * r) * 4);
    vreg[r] = *(const float4*)(vb + (size_t)kc * 4096 + (kf + 4 * r) * 4);
  }

  for (int tile = 0; tile < 64; ++tile) {
    __syncthreads();  // prior tile's P/V reads done (and Q staged on iter 0)

    #pragma unroll
    for (int r = 0; r < 4; ++r) {
      *(float4*)(kp_lds + kc * 68 + (kf + 4 * r) * 4) = kreg[r];
      *(float4*)(vt_lds + kc * 68 + (((kf + 4 * r) ^ vswz) * 4)) = vreg[r];
    }
    __syncthreads();  // tiles ready
    // prefetch AFTER barrier: loads stay in flight under QK+softmax+PV
    if (tile < 63) {
      const int m0 = (tile + 1) * 64;
      #pragma unroll
      for (int r = 0; r < 4; ++r) {
        kreg[r] = *(const float4*)(kb + (size_t)kc * 4096 + m0 + (kf + 4 * r) * 4);
        vreg[r] = *(const float4*)(vb + (size_t)kc * 4096 + m0 + (kf + 4 * r) * 4);
      }
    }

    // ---- QK: s[i][j] = sum_c Q[c][4ng+i] * K[c][4mg+j]  (R15 verbatim)
    float s[4][4] = {{0.f}};
    #pragma unroll 8
    for (int c = 0; c < 64; ++c) {
      const float4 q4 = *(const float4*)(qt_lds + c * 68 + 4 * ng);
      const float4 k4 = *(const float4*)(kp_lds + c * 68 + 4 * mg);
      const float qa[4] = {q4.x, q4.y, q4.z, q4.w};
      const float ka[4] = {k4.x, k4.y, k4.z, k4.w};
      #pragma unroll
      for (int i = 0; i < 4; ++i)
        #pragma unroll
        for (int j = 0; j < 4; ++j)
          s[i][j] += qa[i] * ka[j];
    }

    // ---- online softmax (per n-row, across 16 mg-lanes)  (R15 verbatim)
    #pragma unroll
    for (int i = 0; i < 4; ++i) {
      float rm = fmaxf(fmaxf(s[i][0], s[i][1]), fmaxf(s[i][2], s[i][3]));
      rm = fmaxf(rm, __shfl_xor(rm, 1));
      rm = fmaxf(rm, __shfl_xor(rm, 2));
      rm = fmaxf(rm, __shfl_xor(rm, 4));
      rm = fmaxf(rm, __shfl_xor(rm, 8));
      const float mn = fmaxf(m_run[i], rm);
      const float al = __expf(m_run[i] - mn);
      m_run[i] = mn;
      float rs = 0.f;
      #pragma unroll
      for (int j = 0; j < 4; ++j) { s[i][j] = __expf(s[i][j] - mn); rs += s[i][j]; }
      rs += __shfl_xor(rs, 1);
      rs += __shfl_xor(rs, 2);
      rs += __shfl_xor(rs, 4);
      rs += __shfl_xor(rs, 8);
      l_run[i] = al * l_run[i] + rs;
      #pragma unroll
      for (int j = 0; j < 4; ++j) acc[i][j] *= al;
    }

    __syncthreads();  // all K reads done before P overwrites kp_lds
    #pragma unroll
    for (int i = 0; i < 4; ++i)
      *(float4*)(kp_lds + (4 * ng + i) * 68 + 4 * mg) =
          make_float4(s[i][0], s[i][1], s[i][2], s[i][3]);
    __syncthreads();

    // ---- PV: acc[i][j] += sum_m P[4ng+i][m] * V[4mg+j][m]
    // V read from [c][m] rows (swizzled granule); same values/order as R15.
    #pragma unroll 4
    for (int m4 = 0; m4 < 16; ++m4) {
      float pa[4][4];
      #pragma unroll
      for (int i = 0; i < 4; ++i) {
        const float4 p4 = *(const float4*)(kp_lds + (4 * ng + i) * 68 + m4 * 4);
        pa[i][0] = p4.x; pa[i][1] = p4.y; pa[i][2] = p4.z; pa[i][3] = p4.w;
      }
      float4 v4[4];
      #pragma unroll
      for (int j = 0; j < 4; ++j) {
        const int row = 4 * mg + j;
        v4[j] = *(const float4*)(vt_lds + row * 68 + ((m4 ^ ((row >> 3) & 7)) * 4));
      }
      #pragma unroll
      for (int i = 0; i < 4; ++i)
        #pragma unroll
        for (int j = 0; j < 4; ++j)
          acc[i][j] += pa[i][0] * v4[j].x + pa[i][1] * v4[j].y +
                       pa[i][2] * v4[j].z + pa[i][3] * v4[j].w;
    }
  }

  // ---- epilogue: normalize, transpose through LDS, coalesced store (R15)
  __syncthreads();
  #pragma unroll
  for (int i = 0; i < 4; ++i) {
    const float inv = 1.f / l_run[i];
    #pragma unroll
    for (int j = 0; j < 4; ++j)
      qt_lds[(4 * mg + j) * 68 + 4 * ng + i] = acc[i][j] * inv;  // [c][n]
  }
  __syncthreads();
  {
    const int c = t >> 2;
    #pragma unroll
    for (int r = 0; r < 4; ++r) {
      const int f4i = (t & 3) + 4 * r;
      *(float4*)(f + ((size_t)b * 64 + c) * 4096 + n0 + f4i * 4) =
          *(const float4*)(qt_lds + c * 68 + f4i * 4);
    }
  }
}

// ---------------------------------------------------------------------------
// conv_r (R26 verbatim; fin is [b][64 c][4096 px]).
__global__ __launch_bounds__(256, 4) void conv_r_f32(
    const float* __restrict__ fin, const float* __restrict__ w,
    const float* __restrict__ bi, const float* __restrict__ g,
    const float* __restrict__ be, const float* __restrict__ mu,
    const float* __restrict__ va, const float* __restrict__ res,
    float* __restrict__ out)
{
  __shared__ float tA[2][CTSZ];

  const int b   = blockIdx.z;
  const int co0 = blockIdx.y * 4;
  const int y0  = blockIdx.x * 16;
  const int t   = threadIdx.x;
  const int ry  = t >> 4;
  const int xg  = t & 15;
  const int x0  = xg * 4;

  float sc[4], sh[4];
  #pragma unroll
  for (int cc = 0; cc < 4; ++cc) {
    const int c = co0 + cc;
    const float iv = g[c] * rsqrtf(va[c] + 1e-5f);
    sc[cc] = iv; sh[cc] = bi[c] * iv + be[c] - mu[c] * iv;
  }

  const float* srcA = fin + (size_t)b * 64 * 4096;
  float4 rA[2][2];
  const int row0 = t >> 4;
  const int row1 = 16 + (t >> 4);
  const int grp  = t & 15;

  #define LOADR(R)                                                            \
    {                                                                         \
      _Pragma("unroll")                                                       \
      for (int s = 0; s < 2; ++s) {                                           \
        const size_t cb = (size_t)((R) * 2 + s) * 4096;                       \
        {                                                                     \
          const int gy = y0 - 1 + row0;                                       \
          float4 a = make_float4(0.f, 0.f, 0.f, 0.f);                         \
          if (gy >= 0 && gy <= 63)                                            \
            a = *(const float4*)(srcA + cb + gy * 64 + grp * 4);              \
          rA[s][0] = a;                                                       \
        }                                                                     \
        if (t < 32) {                                                         \
          const int gy = y0 - 1 + row1;                                       \
          float4 a = make_float4(0.f, 0.f, 0.f, 0.f);                         \
          if (gy >= 0 && gy <= 63)                                            \
            a = *(const float4*)(srcA + cb + gy * 64 + grp * 4);              \
          rA[s][1] = a;                                                       \
        }                                                                     \
      }                                                                       \
    }

  float acc[4][4] = {{0.f}};
  LOADR(0);

  for (int r = 0; r < 32; ++r) {
    __syncthreads();
    #pragma unroll
    for (int s = 0; s < 2; ++s) {
      *(float4*)(&tA[s][row0 * CTSTR + grp * 4]) = rA[s][0];
      if (t < 32)
        *(float4*)(&tA[s][row1 * CTSTR + grp * 4]) = rA[s][1];
    }
    __syncthreads();
    if (r < 31) LOADR(r + 1);

    #pragma unroll
    for (int s = 0; s < 2; ++s) {
      const size_t wb = (size_t)co0 * 576 + (size_t)(r * 2 + s) * 9;
      float w0_[9], w1_[9], w2_[9], w3_[9];
      #pragma unroll
      for (int j = 0; j < 9; ++j) {
        w0_[j] = w[wb + j];
        w1_[j] = w[wb + 576 + j];
        w2_[j] = w[wb + 1152 + j];
        w3_[j] = w[wb + 1728 + j];
      }

      #pragma unroll
      for (int ky = 0; ky < 3; ++ky) {
        const float4 a4 = *(const float4*)(&tA[s][(ry + ky) * CTSTR + x0]);
        const float ca[6] = {dpp_left(a4.w), a4.x, a4.y, a4.z, a4.w, dpp_right(a4.x)};
        const int kb3 = ky * 3;
        #pragma unroll
        for (int px = 0; px < 4; ++px) {
          acc[0][px] += ca[px] * w0_[kb3] + ca[px + 1] * w0_[kb3 + 1] + ca[px + 2] * w0_[kb3 + 2];
          acc[1][px] += ca[px] * w1_[kb3] + ca[px + 1] * w1_[kb3 + 1] + ca[px + 2] * w1_[kb3 + 2];
          acc[2][px] += ca[px] * w2_[kb3] + ca[px + 1] * w2_[kb3 + 1] + ca[px + 2] * w2_[kb3 + 2];
          acc[3][px] += ca[px] * w3_[kb3] + ca[px + 1] * w3_[kb3 + 1] + ca[px + 2] * w3_[kb3 + 2];
        }
      }
    }
  }

  const size_t ob = ((size_t)b * 256 + co0) * 4096 + (size_t)(y0 + ry) * 64 + x0;
  #pragma unroll
  for (int cc = 0; cc < 4; ++cc) {
    const float4 rv = *(const float4*)(res + ob + (size_t)cc * 4096);
    float4 o;
    o.x = rv.x + fmaxf(acc[cc][0] * sc[cc] + sh[cc], 0.f);
    o.y = rv.y + fmaxf(acc[cc][1] * sc[cc] + sh[cc], 0.f);
    o.z = rv.z + fmaxf(acc[cc][2] * sc[cc] + sh[cc], 0.f);
    o.w = rv.w + fmaxf(acc[cc][3] * sc[cc] + sh[cc], 0.f);
    *(float4*)(out + ob + (size_t)cc * 4096) = o;
  }
}

// ---------------------------------------------------------------------------
extern "C" void kernel_launch(void* const* d_in, const int* in_sizes, int n_in,
                              void* d_out, int out_size, void* d_ws, size_t ws_size,
                              hipStream_t stream) {
  const float* f1 = (const float*)d_in[0];
  const float* f2 = (const float*)d_in[1];
  const float* qw = (const float*)d_in[2];  const float* qb = (const float*)d_in[3];
  const float* qg = (const float*)d_in[4];  const float* qbe = (const float*)d_in[5];
  const float* qm = (const float*)d_in[6];  const float* qv = (const float*)d_in[7];
  const float* kw = (const float*)d_in[8];  const float* kb = (const float*)d_in[9];
  const float* kg = (const float*)d_in[10]; const float* kbe = (const float*)d_in[11];
  const float* km = (const float*)d_in[12]; const float* kv = (const float*)d_in[13];
  const float* vw = (const float*)d_in[14]; const float* vb = (const float*)d_in[15];
  const float* vg = (const float*)d_in[16]; const float* vbe = (const float*)d_in[17];
  const float* vm = (const float*)d_in[18]; const float* vv = (const float*)d_in[19];
  const float* rw = (const float*)d_in[20]; const float* rb = (const float*)d_in[21];
  const float* rg = (const float*)d_in[22]; const float* rbe = (const float*)d_in[23];
  const float* rm = (const float*)d_in[24]; const float* rv = (const float*)d_in[25];

  hipStreamCaptureStatus cap = hipStreamCaptureStatusNone;
  unsigned long long capid = 0;
  const hipError_t ce = hipStreamGetCaptureInfo(stream, &cap, &capid);
  const bool capturing = (ce == hipSuccess) && (cap != hipStreamCaptureStatusNone);

  // Workspace: q,k,v,f fp32 [4][64][4096] channel-major, 4 MB each.
  const size_t SZ1 = (size_t)4 * 64 * 4096 * 4;
  float* qp = (float*)d_ws;
  float* kp = (float*)((char*)d_ws + SZ1);
  float* vp = (float*)((char*)d_ws + 2 * SZ1);
  float* fp = (float*)((char*)d_ws + 3 * SZ1);

  convqkv_f32<<<dim3(4, 32, 4), 256, 0, stream>>>(
      f1, f2,
      qw, qb, qg, qbe, qm, qv,
      kw, kb, kg, kbe, km, kv,
      vw, vb, vg, vbe, vm, vv,
      qp, kp, vp);
  attention_flash_f32<<<dim3(256), 256, 0, stream>>>(qp, kp, vp, fp);
  conv_r_f32<<<dim3(4, 64, 4), 256, 0, stream>>>(fp, rw, rb, rg, rbe, rm, rv,
                                                 f1, (float*)d_out);

  if (!capturing) {
    const hipError_t le = hipGetLastError();
    const hipError_t se = hipStreamSynchronize(stream);
    float h[4] = {0, 0, 0, 0};
    (void)hipMemcpy(h, d_out, 16, hipMemcpyDeviceToHost);
    fprintf(stderr,
        "ATHENA_R27 4x4-cleanV le=%d sync=%d out=[%g %g %g %g]\n",
        (int)le, (int)se, h[0], h[1], h[2], h[3]);
    fflush(stderr);
  }
}